// Round 19
// baseline (209.772 us; speedup 1.0000x reference)
//
#include <hip/hip_runtime.h>
#include <hip/hip_bf16.h>

typedef __bf16 bf16x8 __attribute__((ext_vector_type(8)));
typedef _Float16 f16x8 __attribute__((ext_vector_type(8)));
typedef _Float16 f16x2 __attribute__((ext_vector_type(2)));
typedef float f32x4 __attribute__((ext_vector_type(4)));

#define B_DIM 16
#define L_DIM 1024
#define H_DIM 4
#define HC 128
#define TI 64
#define WPITCH 136   // bf16 elems; 272B rows, 16B-aligned

// job ids: [0,256) proj unit (64 rows); [256,512) mask tile (64 rows);
// [512,768) attn tile. sync[]: [0]=job ctr; [1..16]=proj ctr per b;
// [32..287]=mask-tile flags.
#define N_JOBS 768

__global__ __launch_bounds__(512, 4) void gat_fused_kernel(
    const float* __restrict__ x, const float* __restrict__ W,
    const float* __restrict__ bias, const float* __restrict__ att_src,
    const float* __restrict__ att_dst, const int* __restrict__ adj,
    _Float16* __restrict__ xpT, _Float16* __restrict__ E1h,
    _Float16* __restrict__ E2h, float* __restrict__ Rr,
    unsigned* __restrict__ mask_g, unsigned* __restrict__ sync,
    float* __restrict__ out)
{
  // union: proj {Wlds 34816 | xh 17408 | xl 17408} = 69632
  //        attn {e1u 8192 | e2u 8192 | msk 11264 ... comb overlay 53248}
  __shared__ __align__(16) char smem[69664];
  unsigned* jobslot = reinterpret_cast<unsigned*>(smem + 69632);

  const int t = threadIdx.x;
  const int wv = t >> 6;
  const int lane = t & 63;
  const int ln15 = lane & 15;
  const int kh = lane >> 4;

  for (;;) {
    __syncthreads();                    // prior job's smem use complete
    if (t == 0) *jobslot = atomicAdd(&sync[0], 1u);
    __syncthreads();
    const unsigned job = *jobslot;
    if (job >= N_JOBS) return;

    if (job < 256u) {
      // ================= proj unit: rows job*64..+63 =================
      __bf16* Wlds = reinterpret_cast<__bf16*>(smem);            // [128][136]
      __bf16* xh   = reinterpret_cast<__bf16*>(smem + 34816);    // [64][136]
      __bf16* xl   = reinterpret_cast<__bf16*>(smem + 52224);    // [64][136]
      const int r0 = (int)job * 64;

#pragma unroll
      for (int p = 0; p < 4; ++p) {     // W: 16384 elems, 32/thr
        const int idx = p * 4096 + t * 8;
        const int n = idx >> 7, k = idx & 127;
        const f32x4 a = *reinterpret_cast<const f32x4*>(W + idx);
        const f32x4 bq = *reinterpret_cast<const f32x4*>(W + idx + 4);
        bf16x8 v;
#pragma unroll
        for (int e = 0; e < 4; ++e) { v[e] = (__bf16)a[e]; v[e + 4] = (__bf16)bq[e]; }
        *reinterpret_cast<bf16x8*>(&Wlds[n * WPITCH + k]) = v;
      }
#pragma unroll
      for (int p = 0; p < 2; ++p) {     // x: 64 rows, hi/lo split
        const int idx = p * 4096 + t * 8;
        const int r = idx >> 7, k = idx & 127;
        const float* xp_ = x + (size_t)(r0 + r) * 128 + k;
        const f32x4 a = *reinterpret_cast<const f32x4*>(xp_);
        const f32x4 bq = *reinterpret_cast<const f32x4*>(xp_ + 4);
        bf16x8 vh, vl;
#pragma unroll
        for (int e = 0; e < 4; ++e) {
          const float fa = a[e], fb = bq[e];
          vh[e] = (__bf16)fa;          vh[e + 4] = (__bf16)fb;
          vl[e] = (__bf16)(fa - (float)vh[e]);
          vl[e + 4] = (__bf16)(fb - (float)vh[e + 4]);
        }
        *reinterpret_cast<bf16x8*>(&xh[r * WPITCH + k]) = vh;
        *reinterpret_cast<bf16x8*>(&xl[r * WPITCH + k]) = vl;
      }
      __syncthreads();

      // wave: rows (wv&3)*16..+15, nc chunks nh..nh+3 (n-half wv>>2)
      const int rowg = (wv & 3) * 16;
      const int nh = (wv >> 2) * 4;
      const int rr = ln15;
      const int g8 = kh * 8;
      f32x4 acc[4] = {};
#pragma unroll
      for (int kk = 0; kk < 4; ++kk) {
        const int ko = kk * 32 + g8;
        const bf16x8 bh = *reinterpret_cast<const bf16x8*>(&xh[(rowg + rr) * WPITCH + ko]);
        const bf16x8 bl = *reinterpret_cast<const bf16x8*>(&xl[(rowg + rr) * WPITCH + ko]);
#pragma unroll
        for (int nc = 0; nc < 4; ++nc) {
          const bf16x8 af = *reinterpret_cast<const bf16x8*>(&Wlds[((nh + nc) * 16 + rr) * WPITCH + ko]);
          acc[nc] = __builtin_amdgcn_mfma_f32_16x16x32_bf16(af, bh, acc[nc], 0, 0, 0);
          acc[nc] = __builtin_amdgcn_mfma_f32_16x16x32_bf16(af, bl, acc[nc], 0, 0, 0);
        }
      }
      const int q4 = kh * 4;
      const int grow = r0 + rowg + rr;
      const int bb = grow >> 10;
      const int lg = grow & 1023;
      float asum[2] = {0.f, 0.f};
      float adsum[2] = {0.f, 0.f};
#pragma unroll
      for (int nc = 0; nc < 4; ++nc) {
        const int n0 = (nh + nc) * 16 + q4;
        const f32x4 bv = *reinterpret_cast<const f32x4*>(bias + n0);
        const f32x4 sv = *reinterpret_cast<const f32x4*>(att_src + n0);
        const f32x4 dv = *reinterpret_cast<const f32x4*>(att_dst + n0);
        const int hl = nc >> 1;
#pragma unroll
        for (int reg = 0; reg < 4; ++reg) {
          const float v = acc[nc][reg] + bv[reg];
          xpT[((size_t)(bb * 128 + n0 + reg)) * 1024 + lg] = (_Float16)v;
          asum[hl]  = fmaf(v, sv[reg], asum[hl]);
          adsum[hl] = fmaf(v, dv[reg], adsum[hl]);
        }
      }
#pragma unroll
      for (int hl = 0; hl < 2; ++hl) {
        asum[hl]  += __shfl_xor(asum[hl], 16);
        asum[hl]  += __shfl_xor(asum[hl], 32);
        adsum[hl] += __shfl_xor(adsum[hl], 16);
        adsum[hl] += __shfl_xor(adsum[hl], 32);
      }
      if (kh == 0) {
#pragma unroll
        for (int hl = 0; hl < 2; ++hl) {
          const int hg = (wv >> 2) * 2 + hl;
          const size_t o = ((size_t)bb * 4 + hg) * 1024 + lg;
          E1h[o] = (_Float16)(16.0f * __expf(asum[hl]));
          E2h[o] = (_Float16)__expf(0.2f * asum[hl]);
          Rr[o]  = 16.0f * __expf(-0.8f * adsum[hl]);
        }
      }
      __threadfence();
      __syncthreads();
      if (t == 0) atomicAdd(&sync[1 + (int)(job >> 4)], 1u);

    } else if (job < 512u) {
      // ================= mask tile: rows (job-256)*64..+63 =================
      const int mbase = ((int)job - 256) * 64;
#pragma unroll
      for (int pass = 0; pass < 4; ++pass) {
        const int row0 = mbase + pass * 16 + wv * 2;
        const int* basep = adj + (size_t)row0 * L_DIM;
        int4 av[8];
#pragma unroll
        for (int c = 0; c < 4; ++c) {
          av[c]     = *reinterpret_cast<const int4*>(basep + c * 256 + lane * 4);
          av[c + 4] = *reinterpret_cast<const int4*>(basep + 1024 + c * 256 + lane * 4);
        }
#pragma unroll
        for (int r = 0; r < 2; ++r) {
          const int row = row0 + r;
          const int i = row & (L_DIM - 1);
#pragma unroll
          for (int c = 0; c < 4; ++c) {
            const int4 u = av[r * 4 + c];
            unsigned b4 = (unsigned)u.x | ((unsigned)u.y << 1) |
                          ((unsigned)u.z << 2) | ((unsigned)u.w << 3);
            unsigned p;
            p = __shfl_xor(b4, 1);
            unsigned b8  = (lane & 1) ? (p | (b4 << 4))   : (b4 | (p << 4));
            p = __shfl_xor(b8, 2);
            unsigned b16 = (lane & 2) ? (p | (b8 << 8))   : (b8 | (p << 8));
            p = __shfl_xor(b16, 4);
            unsigned b32 = (lane & 4) ? (p | (b16 << 16)) : (b16 | (p << 16));
            const int widx = c * 8 + (lane >> 3);
            if ((i >> 5) == widx) b32 |= (1u << (i & 31));
            if ((lane & 7) == 0) mask_g[(size_t)row * 32 + widx] = b32;
          }
        }
      }
      __threadfence();
      __syncthreads();
      if (t == 0) atomicExch(&sync[32 + ((int)job - 256)], 1u);

    } else {
      // ================= attn tile (R12-proven body) =================
      const int tile = (int)job - 512;
      const int b  = tile >> 4;
      const int i0 = (tile & 15) * TI;
      if (t == 0) {
        while (atomicAdd(&sync[1 + b], 0u) < 16u) __builtin_amdgcn_s_sleep(8);
        while (atomicAdd(&sync[32 + tile], 0u) == 0u) __builtin_amdgcn_s_sleep(8);
      }
      __syncthreads();
      __threadfence();                 // acquire: see producers' data

      unsigned* e1u = reinterpret_cast<unsigned*>(smem);           // [4][512]
      unsigned* e2u = reinterpret_cast<unsigned*>(smem + 8192);    // [4][512]
      unsigned char* msk = reinterpret_cast<unsigned char*>(smem + 16384); // [64][176]
      float* comb = reinterpret_cast<float*>(smem);                // overlay

      {
        const int r = t >> 3, sg = t & 7;
        const uint4 m = *reinterpret_cast<const uint4*>(
            mask_g + ((size_t)b * L_DIM + i0 + r) * 32 + sg * 4);
        *reinterpret_cast<uint4*>(&msk[r * 176 + sg * 16]) = m;
      }
      {
        const int sh = t >> 7;
        const int off = (t & 127) * 8;
        const _Float16* p1 = E1h + ((size_t)(b * H_DIM + sh)) * L_DIM + off;
        const _Float16* p2 = E2h + ((size_t)(b * H_DIM + sh)) * L_DIM + off;
        *reinterpret_cast<uint4*>(&e1u[sh * 512 + (off >> 1)]) = *reinterpret_cast<const uint4*>(p1);
        *reinterpret_cast<uint4*>(&e2u[sh * 512 + (off >> 1)]) = *reinterpret_cast<const uint4*>(p2);
      }
      __syncthreads();

      const int h  = wv >> 1;
      const int jh = wv & 1;
      const int jb = kh * 8;
      const int base = jh * 512;
      const float* RrB = Rr + ((size_t)(b * H_DIM + h)) * L_DIM + i0 + ln15;
      f16x2 R2g[4];
#pragma unroll
      for (int g = 0; g < 4; ++g) {
        const _Float16 rh = (_Float16)RrB[g * 16];
        R2g[g][0] = rh; R2g[g][1] = rh;
      }
      const _Float16* xb0 = xpT + ((size_t)(b * 128 + h * 32 + ln15)) * 1024 + base;
      const _Float16* xb1 = xb0 + 16 * 1024;

      f32x4 acc0[4] = {}, acc1[4] = {}, accS[4] = {};
      f16x8 ones16;
#pragma unroll
      for (int e = 0; e < 8; ++e) ones16[e] = (_Float16)1.0f;

      uint4 pf0[2], pf1[2];
#pragma unroll
      for (int s = 0; s < 2; ++s) {
        pf0[s] = *reinterpret_cast<const uint4*>(xb0 + s * 32 + jb);
        pf1[s] = *reinterpret_cast<const uint4*>(xb1 + s * 32 + jb);
      }
      uint4 u1c = *reinterpret_cast<const uint4*>(&e1u[h * 512 + ((base + jb) >> 1)]);
      uint4 u2c = *reinterpret_cast<const uint4*>(&e2u[h * 512 + ((base + jb) >> 1)]);

#pragma unroll 4
      for (int kr = 0; kr < 512; kr += 32) {
        const int k0 = base + kr;
        const int wb = jh * 64 + ((kr >> 5) << 2);
        unsigned mb[4];
#pragma unroll
        for (int g = 0; g < 4; ++g) {
          const unsigned w32 = *reinterpret_cast<const unsigned*>(
              &msk[(g * 16 + ln15) * 176 + wb]);
          mb[g] = (w32 >> (kh * 8)) & 0xffu;
        }
        const int kn = (((k0 + 32) & 1023) + jb) >> 1;
        const uint4 u1n = *reinterpret_cast<const uint4*>(&e1u[h * 512 + kn]);
        const uint4 u2n = *reinterpret_cast<const uint4*>(&e2u[h * 512 + kn]);

        const int sl = (kr >> 5) & 1;
        const uint4 bb0 = pf0[sl];
        const uint4 bb1 = pf1[sl];
        pf0[sl] = *reinterpret_cast<const uint4*>(xb0 + kr + 64 + jb);  // over-read safe (ws)
        pf1[sl] = *reinterpret_cast<const uint4*>(xb1 + kr + 64 + jb);

        const unsigned uu1[4] = {u1c.x, u1c.y, u1c.z, u1c.w};
        const unsigned uu2[4] = {u2c.x, u2c.y, u2c.z, u2c.w};
        unsigned rg[4][4];
#pragma unroll
        for (int q = 0; q < 4; ++q) {
          f16x2 a, ee;
          __builtin_memcpy(&a,  &uu1[q], 4);
          __builtin_memcpy(&ee, &uu2[q], 4);
#pragma unroll
          for (int g = 0; g < 4; ++g) {
            const f16x2 pr = ee * R2g[g];                         // v_pk_mul_f16
            const f16x2 mx = __builtin_elementwise_max(a, pr);    // v_pk_max_f16
            unsigned mu;
            __builtin_memcpy(&mu, &mx, 4);
            const unsigned mlo = (mb[g] & (1u << (2 * q)))     ? 0xFFFFu : 0u;
            const unsigned mhi = (mb[g] & (1u << (2 * q + 1))) ? 0xFFFF0000u : 0u;
            rg[g][q] = mu & (mlo | mhi);
          }
        }
        f16x8 b0h, b1h;
        __builtin_memcpy(&b0h, &bb0, 16);
        __builtin_memcpy(&b1h, &bb1, 16);
#pragma unroll
        for (int g = 0; g < 4; ++g) {
          const uint4 afu = {rg[g][0], rg[g][1], rg[g][2], rg[g][3]};
          f16x8 af;
          __builtin_memcpy(&af, &afu, 16);
          acc0[g] = __builtin_amdgcn_mfma_f32_16x16x32_f16(af, b0h, acc0[g], 0, 0, 0);
          acc1[g] = __builtin_amdgcn_mfma_f32_16x16x32_f16(af, b1h, acc1[g], 0, 0, 0);
          accS[g] = __builtin_amdgcn_mfma_f32_16x16x32_f16(af, ones16, accS[g], 0, 0, 0);
        }
        u1c = u1n; u2c = u2n;
      }

      __syncthreads();                  // e/msk reads done before comb overlay
      if (jh == 1) {
#pragma unroll
        for (int g = 0; g < 4; ++g) {
          float* cp = &comb[((h * 4 + g) * 64 + lane) * 13];
#pragma unroll
          for (int e = 0; e < 4; ++e) {
            cp[e]     = acc0[g][e];
            cp[4 + e] = acc1[g][e];
            cp[8 + e] = accS[g][e];
          }
        }
      }
      __syncthreads();
      if (jh == 0) {
#pragma unroll
        for (int g = 0; g < 4; ++g) {
          const float* cp = &comb[((h * 4 + g) * 64 + lane) * 13];
#pragma unroll
          for (int reg = 0; reg < 4; ++reg) {
            const float s = accS[g][reg] + cp[8 + reg];
            const float rs = 1.0f / s;
            float* op = out + ((size_t)(b * L_DIM + i0 + g * 16 + kh * 4 + reg)) * HC + h * 32;
            op[ln15]      = (acc0[g][reg] + cp[reg])     * rs;
            op[16 + ln15] = (acc1[g][reg] + cp[4 + reg]) * rs;
          }
        }
      }
    }
  }
}

extern "C" void kernel_launch(void* const* d_in, const int* in_sizes, int n_in,
                              void* d_out, int out_size, void* d_ws, size_t ws_size,
                              hipStream_t stream) {
  (void)in_sizes; (void)n_in; (void)out_size; (void)ws_size;
  const float* x        = (const float*)d_in[0];
  const int*   adj      = (const int*)d_in[1];
  const float* W        = (const float*)d_in[2];
  const float* bias     = (const float*)d_in[3];
  const float* att_src  = (const float*)d_in[4];
  const float* att_dst  = (const float*)d_in[5];
  float* out = (float*)d_out;

  char* ws = (char*)d_ws;
  _Float16* xpT    = (_Float16*)ws;                                      // 4 MiB
  _Float16* E1h    = (_Float16*)(ws + (size_t)4 * 1024 * 1024);          // 128 KiB
  _Float16* E2h    = (_Float16*)(ws + (size_t)4 * 1024 * 1024 + 131072); // 128 KiB
  float*    Rr     = (float*)(ws + (size_t)4 * 1024 * 1024 + 262144);    // 256 KiB
  unsigned* mask_g = (unsigned*)(ws + (size_t)4 * 1024 * 1024 + 524288); // 2 MiB
  unsigned* syncb  = (unsigned*)(ws + (size_t)7 * 1024 * 1024);          // 4 KiB

  hipMemsetAsync(syncb, 0, 4096, stream);
  hipLaunchKernelGGL(gat_fused_kernel, dim3(512), dim3(512), 0, stream,
                     x, W, bias, att_src, att_dst, adj,
                     xpT, E1h, E2h, Rr, mask_g, syncb, out);
}

// Round 20
// 36.523 us; speedup vs baseline: 5.7436x; 5.7436x over previous
//
#include <hip/hip_runtime.h>
#include <hip/hip_bf16.h>

typedef __bf16 bf16x8 __attribute__((ext_vector_type(8)));
typedef _Float16 f16x8 __attribute__((ext_vector_type(8)));
typedef _Float16 f16x2 __attribute__((ext_vector_type(2)));
typedef float f32x4 __attribute__((ext_vector_type(4)));

#define B_DIM 16
#define L_DIM 1024
#define H_DIM 4
#define HC 128
#define TI 64
#define WPITCH 136   // bf16 elems; 272B rows, 16B-aligned
#define PROJ_BLOCKS 256

// ---------------------------------------------------------------------------
// Kernel 1 (heterogeneous prep, R16-proven): blocks 0..255 = projection
// (64 rows each), blocks 256..2303 = adjacency bit-pack (8 rows each).
// Proj blocks dispatch FIRST so CUs overlap the 64MB adj stream with proj's
// MFMA compute; kills one launch gap.
// ---------------------------------------------------------------------------
__global__ __launch_bounds__(256) void prep_kernel(
    const float* __restrict__ x, const float* __restrict__ W,
    const float* __restrict__ bias, const float* __restrict__ att_src,
    const float* __restrict__ att_dst, const int* __restrict__ adj,
    _Float16* __restrict__ xpT, _Float16* __restrict__ E1h,
    _Float16* __restrict__ E2h, float* __restrict__ Rr,
    unsigned* __restrict__ mask_g)
{
  __shared__ __align__(16) __bf16 Wlds[128 * WPITCH];   // 34.8 KB
  __shared__ __align__(16) __bf16 xh[64 * WPITCH];      // 17.4 KB
  __shared__ __align__(16) __bf16 xl[64 * WPITCH];      // 17.4 KB
  const int bid = blockIdx.x;
  const int t = threadIdx.x;
  const int wv = t >> 6, lane = t & 63;

  if (bid >= PROJ_BLOCKS) {
    // ---- mask role: rows (bid-256)*8 + wv*2 + {0,1} ----
    const int row0 = (bid - PROJ_BLOCKS) * 8 + wv * 2;
    const int* base = adj + (size_t)row0 * L_DIM;
    int4 av[8];
#pragma unroll
    for (int c = 0; c < 4; ++c) {
      av[c]     = *reinterpret_cast<const int4*>(base + c * 256 + lane * 4);
      av[c + 4] = *reinterpret_cast<const int4*>(base + 1024 + c * 256 + lane * 4);
    }
#pragma unroll
    for (int r = 0; r < 2; ++r) {
      const int row = row0 + r;
      const int i = row & (L_DIM - 1);
#pragma unroll
      for (int c = 0; c < 4; ++c) {
        const int4 u = av[r * 4 + c];
        unsigned b4 = (unsigned)u.x | ((unsigned)u.y << 1) |
                      ((unsigned)u.z << 2) | ((unsigned)u.w << 3);
        unsigned p;
        p = __shfl_xor(b4, 1);
        unsigned b8  = (lane & 1) ? (p | (b4 << 4))   : (b4 | (p << 4));
        p = __shfl_xor(b8, 2);
        unsigned b16 = (lane & 2) ? (p | (b8 << 8))   : (b8 | (p << 8));
        p = __shfl_xor(b16, 4);
        unsigned b32 = (lane & 4) ? (p | (b16 << 16)) : (b16 | (p << 16));
        const int widx = c * 8 + (lane >> 3);
        if ((i >> 5) == widx) b32 |= (1u << (i & 31));
        if ((lane & 7) == 0) mask_g[(size_t)row * 32 + widx] = b32;
      }
    }
    return;
  }

  // ---- proj role: rows bid*64 .. +63; wave w owns rows w*16..+15 ----
  const int r0 = bid * 64;
#pragma unroll
  for (int p = 0; p < 8; ++p) {
    const int idx = p * 2048 + t * 8;
    const int n = idx >> 7, k = idx & 127;
    const f32x4 a = *reinterpret_cast<const f32x4*>(W + idx);
    const f32x4 b = *reinterpret_cast<const f32x4*>(W + idx + 4);
    bf16x8 v;
#pragma unroll
    for (int e = 0; e < 4; ++e) { v[e] = (__bf16)a[e]; v[e + 4] = (__bf16)b[e]; }
    *reinterpret_cast<bf16x8*>(&Wlds[n * WPITCH + k]) = v;
  }
#pragma unroll
  for (int p = 0; p < 4; ++p) {
    const int idx = p * 2048 + t * 8;
    const int r = idx >> 7, k = idx & 127;
    const float* xp_ = x + (size_t)(r0 + r) * 128 + k;
    const f32x4 a = *reinterpret_cast<const f32x4*>(xp_);
    const f32x4 b = *reinterpret_cast<const f32x4*>(xp_ + 4);
    bf16x8 vh, vl;
#pragma unroll
    for (int e = 0; e < 4; ++e) {
      const float fa = a[e], fb = b[e];
      vh[e] = (__bf16)fa;          vh[e + 4] = (__bf16)fb;
      vl[e] = (__bf16)(fa - (float)vh[e]);
      vl[e + 4] = (__bf16)(fb - (float)vh[e + 4]);
    }
    *reinterpret_cast<bf16x8*>(&xh[r * WPITCH + k]) = vh;
    *reinterpret_cast<bf16x8*>(&xl[r * WPITCH + k]) = vl;
  }
  __syncthreads();

  const int rr = lane & 15;
  const int g8 = (lane >> 4) * 8;
  f32x4 acc[8] = {};
#pragma unroll
  for (int kk = 0; kk < 4; ++kk) {
    const int ko = kk * 32 + g8;
    const bf16x8 bh = *reinterpret_cast<const bf16x8*>(&xh[(wv * 16 + rr) * WPITCH + ko]);
    const bf16x8 bl = *reinterpret_cast<const bf16x8*>(&xl[(wv * 16 + rr) * WPITCH + ko]);
#pragma unroll
    for (int nc = 0; nc < 8; ++nc) {
      const bf16x8 af = *reinterpret_cast<const bf16x8*>(&Wlds[(nc * 16 + rr) * WPITCH + ko]);
      acc[nc] = __builtin_amdgcn_mfma_f32_16x16x32_bf16(af, bh, acc[nc], 0, 0, 0);
      acc[nc] = __builtin_amdgcn_mfma_f32_16x16x32_bf16(af, bl, acc[nc], 0, 0, 0);
    }
  }

  const int q4 = (lane >> 4) * 4;
  const int grow = r0 + wv * 16 + rr;
  const int bb = grow >> 10;
  const int lg = grow & 1023;
  float asum[4] = {0.f, 0.f, 0.f, 0.f};
  float adsum[4] = {0.f, 0.f, 0.f, 0.f};
#pragma unroll
  for (int nc = 0; nc < 8; ++nc) {
    const int n0 = nc * 16 + q4;
    const f32x4 bv = *reinterpret_cast<const f32x4*>(bias + n0);
    const f32x4 sv = *reinterpret_cast<const f32x4*>(att_src + n0);
    const f32x4 dv = *reinterpret_cast<const f32x4*>(att_dst + n0);
    const int h = nc >> 1;
#pragma unroll
    for (int reg = 0; reg < 4; ++reg) {
      const float v = acc[nc][reg] + bv[reg];
      const int n = n0 + reg;
      xpT[((size_t)bb * 128 + n) * 1024 + lg] = (_Float16)v;
      asum[h]  = fmaf(v, sv[reg], asum[h]);
      adsum[h] = fmaf(v, dv[reg], adsum[h]);
    }
  }
#pragma unroll
  for (int h = 0; h < 4; ++h) {
    asum[h]  += __shfl_xor(asum[h], 16);
    asum[h]  += __shfl_xor(asum[h], 32);
    adsum[h] += __shfl_xor(adsum[h], 16);
    adsum[h] += __shfl_xor(adsum[h], 32);
  }
  if ((lane >> 4) == 0) {
#pragma unroll
    for (int h = 0; h < 4; ++h) {
      const size_t o = ((size_t)bb * 4 + h) * 1024 + lg;
      E1h[o] = (_Float16)(16.0f * __expf(asum[h]));
      E2h[o] = (_Float16)__expf(0.2f * asum[h]);
      Rr[o]  = 16.0f * __expf(-0.8f * adsum[h]);
    }
  }
}

// ---------------------------------------------------------------------------
// Kernel 2 (flash attn, R17 + two micro-opts):
//   (a) xpT 4-deep ring fill issued BEFORE the staging barrier (global loads
//       independent of LDS staging -> their L2 latency hides under barrier).
//   (b) s_setprio(1) around the 12-MFMA cluster (T5: helps when waves are
//       independent/non-barrier-synced, as here).
//   Everything else identical to R17 (best measured: 37.6us total).
// ---------------------------------------------------------------------------
__global__ __launch_bounds__(512, 2) void gat_attn_kernel(
    const unsigned* __restrict__ mask_g, const _Float16* __restrict__ xpT,
    const _Float16* __restrict__ E1h, const _Float16* __restrict__ E2h,
    const float* __restrict__ Rr, float* __restrict__ out)
{
  // phase 1: e1u[4][512] | e2u[4][512] | msk[64][176]  (27.6 KB)
  // phase 2 (after barrier): comb[4][4][64][13] floats  (53,248 B exact)
  __shared__ __align__(16) char smem[53248];
  unsigned* e1u = reinterpret_cast<unsigned*>(smem);
  unsigned* e2u = reinterpret_cast<unsigned*>(smem + 8192);
  unsigned char* msk = reinterpret_cast<unsigned char*>(smem + 16384);
  float* comb = reinterpret_cast<float*>(smem);

  const int wg  = blockIdx.x;     // 256 blocks
  const int xcd = wg & 7;
  const int idx = wg >> 3;
  const int b   = xcd * 2 + (idx & 1);
  const int i0  = (idx >> 1) * TI;

  const int t = threadIdx.x;
  const int wv = t >> 6;        // 0..7
  const int lane = t & 63;
  const int h  = wv >> 1;       // head
  const int jh = wv & 1;        // j-half

  const int ln15 = lane & 15;
  const int kh = lane >> 4;
  const int jb = kh * 8;
  const int base = jh * 512;
  const _Float16* xb0 = xpT + ((size_t)(b * 128 + h * 32 + ln15)) * 1024 + base;
  const _Float16* xb1 = xb0 + 16 * 1024;

  // ---- (a) issue xpT ring fill FIRST: overlaps the staging barrier ----
  uint4 pf0[4], pf1[4];
#pragma unroll
  for (int s = 0; s < 4; ++s) {
    pf0[s] = *reinterpret_cast<const uint4*>(xb0 + s * 32 + jb);
    pf1[s] = *reinterpret_cast<const uint4*>(xb1 + s * 32 + jb);
  }
  const float* RrB = Rr + ((size_t)(b * H_DIM + h)) * L_DIM + i0 + ln15;
  f16x2 R2g[4];
#pragma unroll
  for (int g = 0; g < 4; ++g) {
    const _Float16 rh = (_Float16)RrB[g * 16];
    R2g[g][0] = rh; R2g[g][1] = rh;
  }

  // ---- staging ----
  {
    const int r = t >> 3, sg = t & 7;        // 64 rows x 8 segs of 16B
    const uint4 m = *reinterpret_cast<const uint4*>(
        mask_g + ((size_t)b * L_DIM + i0 + r) * 32 + sg * 4);
    *reinterpret_cast<uint4*>(&msk[r * 176 + sg * 16]) = m;
  }
  {
    const int sh = t >> 7;          // head for staging
    const int off = (t & 127) * 8;  // element offset within head slice
    const _Float16* p1 = E1h + ((size_t)(b * H_DIM + sh)) * L_DIM + off;
    const _Float16* p2 = E2h + ((size_t)(b * H_DIM + sh)) * L_DIM + off;
    *reinterpret_cast<uint4*>(&e1u[sh * 512 + (off >> 1)]) = *reinterpret_cast<const uint4*>(p1);
    *reinterpret_cast<uint4*>(&e2u[sh * 512 + (off >> 1)]) = *reinterpret_cast<const uint4*>(p2);
  }
  __syncthreads();

  f32x4 acc0[4] = {}, acc1[4] = {}, accS[4] = {};
  f16x8 ones16;
#pragma unroll
  for (int e = 0; e < 8; ++e) ones16[e] = (_Float16)1.0f;

  // 2-deep e-read ring (prefetch 64 j ahead; wrapped tail loads unused)
  uint4 u1r[2], u2r[2];
#pragma unroll
  for (int s = 0; s < 2; ++s) {
    const int ke = (base + s * 32 + jb) >> 1;
    u1r[s] = *reinterpret_cast<const uint4*>(&e1u[h * 512 + ke]);
    u2r[s] = *reinterpret_cast<const uint4*>(&e2u[h * 512 + ke]);
  }
  uint4 mwc[4];   // per-group mask words, refreshed every 4 iters (128 j)

#pragma unroll 4
  for (int kr = 0; kr < 512; kr += 32) {
    const int tm = (kr >> 5) & 3;
    if (tm == 0) {
#pragma unroll
      for (int g = 0; g < 4; ++g)
        mwc[g] = *reinterpret_cast<const uint4*>(
            &msk[(g * 16 + ln15) * 176 + jh * 64 + (kr >> 7) * 16]);
    }
    unsigned mb[4];
#pragma unroll
    for (int g = 0; g < 4; ++g) {
      const unsigned w32 = (tm == 0) ? mwc[g].x : (tm == 1) ? mwc[g].y
                         : (tm == 2) ? mwc[g].z : mwc[g].w;
      mb[g] = (w32 >> (kh * 8)) & 0xffu;
    }

    // consume e-ring slot, refill 2 iters ahead (wrap keeps addr in-bounds)
    const int sl2 = (kr >> 5) & 1;
    const uint4 u1c = u1r[sl2];
    const uint4 u2c = u2r[sl2];
    const int kn = (((base + kr + 64) & 1023) + jb) >> 1;
    u1r[sl2] = *reinterpret_cast<const uint4*>(&e1u[h * 512 + kn]);
    u2r[sl2] = *reinterpret_cast<const uint4*>(&e2u[h * 512 + kn]);

    // consume xpT ring slot, refill 4 iters ahead (over-read lands in ws)
    const int sl = (kr >> 5) & 3;
    const uint4 bb0 = pf0[sl];
    const uint4 bb1 = pf1[sl];
    pf0[sl] = *reinterpret_cast<const uint4*>(xb0 + kr + 128 + jb);
    pf1[sl] = *reinterpret_cast<const uint4*>(xb1 + kr + 128 + jb);

    const unsigned uu1[4] = {u1c.x, u1c.y, u1c.z, u1c.w};
    const unsigned uu2[4] = {u2c.x, u2c.y, u2c.z, u2c.w};
    unsigned rg[4][4];
#pragma unroll
    for (int q = 0; q < 4; ++q) {
      f16x2 a, ee;
      __builtin_memcpy(&a,  &uu1[q], 4);
      __builtin_memcpy(&ee, &uu2[q], 4);
#pragma unroll
      for (int g = 0; g < 4; ++g) {
        const f16x2 pr = ee * R2g[g];                         // v_pk_mul_f16
        const f16x2 mx = __builtin_elementwise_max(a, pr);    // v_pk_max_f16
        unsigned mu;
        __builtin_memcpy(&mu, &mx, 4);
        const unsigned mlo = (mb[g] & (1u << (2 * q)))     ? 0xFFFFu : 0u;
        const unsigned mhi = (mb[g] & (1u << (2 * q + 1))) ? 0xFFFF0000u : 0u;
        rg[g][q] = mu & (mlo | mhi);
      }
    }
    f16x8 b0h, b1h;
    __builtin_memcpy(&b0h, &bb0, 16);
    __builtin_memcpy(&b1h, &bb1, 16);
    __builtin_amdgcn_s_setprio(1);            // (b) favor MFMA cluster
#pragma unroll
    for (int g = 0; g < 4; ++g) {
      const uint4 afu = {rg[g][0], rg[g][1], rg[g][2], rg[g][3]};
      f16x8 af;
      __builtin_memcpy(&af, &afu, 16);
      acc0[g] = __builtin_amdgcn_mfma_f32_16x16x32_f16(af, b0h, acc0[g], 0, 0, 0);
      acc1[g] = __builtin_amdgcn_mfma_f32_16x16x32_f16(af, b1h, acc1[g], 0, 0, 0);
      accS[g] = __builtin_amdgcn_mfma_f32_16x16x32_f16(af, ones16, accS[g], 0, 0, 0);
    }
    __builtin_amdgcn_s_setprio(0);
  }

  // ---- combine: jh=1 dumps partials; jh=0 adds, normalizes, stores ----
  __syncthreads();                       // e/msk reads complete before overlay
  if (jh == 1) {
#pragma unroll
    for (int g = 0; g < 4; ++g) {
      float* cp = &comb[((h * 4 + g) * 64 + lane) * 13];
#pragma unroll
      for (int e = 0; e < 4; ++e) {
        cp[e]     = acc0[g][e];
        cp[4 + e] = acc1[g][e];
        cp[8 + e] = accS[g][e];
      }
    }
  }
  __syncthreads();
  if (jh == 0) {
#pragma unroll
    for (int g = 0; g < 4; ++g) {
      const float* cp = &comb[((h * 4 + g) * 64 + lane) * 13];
#pragma unroll
      for (int reg = 0; reg < 4; ++reg) {
        const float s = accS[g][reg] + cp[8 + reg];
        const float rs = 1.0f / s;
        float* op = out + ((size_t)(b * L_DIM + i0 + g * 16 + kh * 4 + reg)) * HC + h * 32;
        op[ln15]      = (acc0[g][reg] + cp[reg])     * rs;
        op[16 + ln15] = (acc1[g][reg] + cp[4 + reg]) * rs;
      }
    }
  }
}

extern "C" void kernel_launch(void* const* d_in, const int* in_sizes, int n_in,
                              void* d_out, int out_size, void* d_ws, size_t ws_size,
                              hipStream_t stream) {
  (void)in_sizes; (void)n_in; (void)out_size; (void)ws_size;
  const float* x        = (const float*)d_in[0];
  const int*   adj      = (const int*)d_in[1];
  const float* W        = (const float*)d_in[2];
  const float* bias     = (const float*)d_in[3];
  const float* att_src  = (const float*)d_in[4];
  const float* att_dst  = (const float*)d_in[5];
  float* out = (float*)d_out;

  char* ws = (char*)d_ws;
  _Float16* xpT    = (_Float16*)ws;                                    // 4 MiB
  _Float16* E1h    = (_Float16*)(ws + (size_t)4 * 1024 * 1024);        // 128 KiB
  _Float16* E2h    = (_Float16*)(ws + (size_t)4 * 1024 * 1024 + 131072);
  float*    Rr     = (float*)(ws + (size_t)4 * 1024 * 1024 + 262144);  // 256 KiB
  unsigned* mask_g = (unsigned*)(ws + (size_t)4 * 1024 * 1024 + 524288); // 2 MiB

  hipLaunchKernelGGL(prep_kernel, dim3(PROJ_BLOCKS + B_DIM * L_DIM / 8), dim3(256), 0, stream,
                     x, W, bias, att_src, att_dst, adj, xpT, E1h, E2h, Rr, mask_g);
  hipLaunchKernelGGL(gat_attn_kernel, dim3(B_DIM * L_DIM / TI), dim3(512), 0, stream,
                     mask_g, xpT, E1h, E2h, Rr, out);
}

// Round 21
// 34.134 us; speedup vs baseline: 6.1456x; 1.0700x over previous
//
#include <hip/hip_runtime.h>
#include <hip/hip_bf16.h>

typedef __bf16 bf16x8 __attribute__((ext_vector_type(8)));
typedef _Float16 f16x8 __attribute__((ext_vector_type(8)));
typedef _Float16 f16x2 __attribute__((ext_vector_type(2)));
typedef float f32x4 __attribute__((ext_vector_type(4)));

#define B_DIM 16
#define L_DIM 1024
#define H_DIM 4
#define HC 128
#define TI 64
#define WPITCH 136   // bf16 elems; 272B rows, 16B-aligned

// ---------------------------------------------------------------------------
// Kernel 1: projection via MFMA (R12-proven, byte-exact). bf16 hi/lo
// compensated core, fp16 outputs, x16 pre-scale for fp16 range.
// ---------------------------------------------------------------------------
__global__ __launch_bounds__(128) void proj_kernel(
    const float* __restrict__ x, const float* __restrict__ W,
    const float* __restrict__ bias, const float* __restrict__ att_src,
    const float* __restrict__ att_dst, _Float16* __restrict__ xpT,
    _Float16* __restrict__ E1h, _Float16* __restrict__ E2h,
    float* __restrict__ Rr)
{
  __shared__ __align__(16) __bf16 Wlds[128 * WPITCH];
  __shared__ __align__(16) __bf16 xh[32 * WPITCH];
  __shared__ __align__(16) __bf16 xl[32 * WPITCH];
  const int t = threadIdx.x;
  const int w = t >> 6;
  const int lane = t & 63;
  const int r0 = blockIdx.x * 32;

#pragma unroll
  for (int p = 0; p < 16; ++p) {
    const int idx = p * 1024 + t * 8;
    const int n = idx >> 7, k = idx & 127;
    const f32x4 a = *reinterpret_cast<const f32x4*>(W + idx);
    const f32x4 b = *reinterpret_cast<const f32x4*>(W + idx + 4);
    bf16x8 v;
#pragma unroll
    for (int e = 0; e < 4; ++e) { v[e] = (__bf16)a[e]; v[e + 4] = (__bf16)b[e]; }
    *reinterpret_cast<bf16x8*>(&Wlds[n * WPITCH + k]) = v;
  }
#pragma unroll
  for (int p = 0; p < 4; ++p) {
    const int idx = p * 1024 + t * 8;
    const int r = idx >> 7, k = idx & 127;
    const float* xp_ = x + (size_t)(r0 + r) * 128 + k;
    const f32x4 a = *reinterpret_cast<const f32x4*>(xp_);
    const f32x4 b = *reinterpret_cast<const f32x4*>(xp_ + 4);
    bf16x8 vh, vl;
#pragma unroll
    for (int e = 0; e < 4; ++e) {
      const float fa = a[e], fb = b[e];
      vh[e] = (__bf16)fa;          vh[e + 4] = (__bf16)fb;
      vl[e] = (__bf16)(fa - (float)vh[e]);
      vl[e + 4] = (__bf16)(fb - (float)vh[e + 4]);
    }
    *reinterpret_cast<bf16x8*>(&xh[r * WPITCH + k]) = vh;
    *reinterpret_cast<bf16x8*>(&xl[r * WPITCH + k]) = vl;
  }
  __syncthreads();

  const int rr = lane & 15;
  const int g8 = (lane >> 4) * 8;
  f32x4 acc[8] = {};
#pragma unroll
  for (int kk = 0; kk < 4; ++kk) {
    const int ko = kk * 32 + g8;
    const bf16x8 bh = *reinterpret_cast<const bf16x8*>(&xh[(w * 16 + rr) * WPITCH + ko]);
    const bf16x8 bl = *reinterpret_cast<const bf16x8*>(&xl[(w * 16 + rr) * WPITCH + ko]);
#pragma unroll
    for (int nc = 0; nc < 8; ++nc) {
      const bf16x8 af = *reinterpret_cast<const bf16x8*>(&Wlds[(nc * 16 + rr) * WPITCH + ko]);
      acc[nc] = __builtin_amdgcn_mfma_f32_16x16x32_bf16(af, bh, acc[nc], 0, 0, 0);
      acc[nc] = __builtin_amdgcn_mfma_f32_16x16x32_bf16(af, bl, acc[nc], 0, 0, 0);
    }
  }

  const int q4 = (lane >> 4) * 4;
  const int grow = r0 + w * 16 + rr;
  const int bb = grow >> 10;
  const int lg = grow & 1023;
  float asum[4] = {0.f, 0.f, 0.f, 0.f};
  float adsum[4] = {0.f, 0.f, 0.f, 0.f};
#pragma unroll
  for (int nc = 0; nc < 8; ++nc) {
    const int n0 = nc * 16 + q4;
    const f32x4 bv = *reinterpret_cast<const f32x4*>(bias + n0);
    const f32x4 sv = *reinterpret_cast<const f32x4*>(att_src + n0);
    const f32x4 dv = *reinterpret_cast<const f32x4*>(att_dst + n0);
    const int h = nc >> 1;
#pragma unroll
    for (int reg = 0; reg < 4; ++reg) {
      const float v = acc[nc][reg] + bv[reg];
      const int n = n0 + reg;
      xpT[((size_t)bb * 128 + n) * 1024 + lg] = (_Float16)v;
      asum[h]  = fmaf(v, sv[reg], asum[h]);
      adsum[h] = fmaf(v, dv[reg], adsum[h]);
    }
  }
#pragma unroll
  for (int h = 0; h < 4; ++h) {
    asum[h]  += __shfl_xor(asum[h], 16);
    asum[h]  += __shfl_xor(asum[h], 32);
    adsum[h] += __shfl_xor(adsum[h], 16);
    adsum[h] += __shfl_xor(adsum[h], 32);
  }
  if ((lane >> 4) == 0) {
#pragma unroll
    for (int h = 0; h < 4; ++h) {
      const size_t o = ((size_t)bb * 4 + h) * 1024 + lg;
      E1h[o] = (_Float16)(16.0f * __expf(asum[h]));
      E2h[o] = (_Float16)__expf(0.2f * asum[h]);
      Rr[o]  = 16.0f * __expf(-0.8f * adsum[h]);
    }
  }
}

// ---------------------------------------------------------------------------
// Kernel 2 (flash attn, adj streamed IN-KERNEL, chunk-pipelined):
//   Wave = (head h, row-half rh): sweeps ALL 1024 j for 2 row-groups, so
//   every wave consumes j-chunks in the same order. j in 8 chunks of 128:
//   per chunk { read chunk masks (1 uint4/row from 2KB dbuf LDS) -> pack
//   NEXT chunk from regs (1 ushort/thread, diag folded) -> issue adj loads
//   for chunk+2 (4 int4/thread, 32KB/block in flight) -> 4 compute iters
//   (6 MFMAs, verified layouts) -> barrier }. adj's 256KB/block (10.4us
//   per-CU BW share) hides under ~20us of compute; mask kernel + mask_g
//   round-trip + combine phase + its 2 barriers are all deleted.
// ---------------------------------------------------------------------------
__global__ __launch_bounds__(512, 2) void gat_attn_kernel(
    const int* __restrict__ adj, const _Float16* __restrict__ xpT,
    const _Float16* __restrict__ E1h, const _Float16* __restrict__ E2h,
    const float* __restrict__ Rr, float* __restrict__ out)
{
  __shared__ __align__(16) unsigned e1u[H_DIM][512];          // 8 KB
  __shared__ __align__(16) unsigned e2u[H_DIM][512];          // 8 KB
  __shared__ __align__(16) unsigned short msk[2][64][8];      // 2 KB dbuf

  const int wg  = blockIdx.x;     // 256 blocks
  const int xcd = wg & 7;
  const int idx = wg >> 3;
  const int b   = xcd * 2 + (idx & 1);
  const int i0  = (idx >> 1) * TI;

  const int t = threadIdx.x;
  const int wv = t >> 6;        // 0..7
  const int lane = t & 63;
  const int h  = wv >> 1;       // head
  const int rh = wv & 1;        // row-half
  const int ln15 = lane & 15;
  const int kh = lane >> 4;
  const int jb = kh * 8;

  // ---- adj pack mapping: thread (row pr, 16-j seg ps) ----
  const int pr = t >> 3;        // 0..63
  const int ps = t & 7;         // 0..7
  const int gi = i0 + pr;
  const int* arow = adj + ((size_t)b * L_DIM + gi) * L_DIM + ps * 16;

  int4 av[4];                   // raw adj for one 16-j segment (64B)
#define LOAD_CHUNK(c)                                                    \
  {                                                                      \
    _Pragma("unroll")                                                    \
    for (int q = 0; q < 4; ++q)                                          \
      av[q] = *reinterpret_cast<const int4*>(arow + (c) * 128 + q * 4);  \
  }
#define PACK_CHUNK(c, buf)                                               \
  {                                                                      \
    unsigned bits = 0;                                                   \
    _Pragma("unroll")                                                    \
    for (int q = 0; q < 4; ++q) {                                        \
      const int4 u = av[q];                                              \
      const unsigned b4 = (unsigned)u.x | ((unsigned)u.y << 1) |         \
                          ((unsigned)u.z << 2) | ((unsigned)u.w << 3);   \
      bits |= b4 << (q * 4);                                             \
    }                                                                    \
    const int d = gi - ((c) * 128 + ps * 16);                            \
    if ((unsigned)d < 16u) bits |= (1u << d);                            \
    msk[buf][pr][ps] = (unsigned short)bits;                             \
  }

  // ---- prologue: chunk0 load+pack, chunk1 load; e1/e2 staging ----
  LOAD_CHUNK(0);
  {
    const int sh = t >> 7;          // head for staging
    const int off = (t & 127) * 8;  // f16 elems
    const _Float16* p1 = E1h + ((size_t)(b * H_DIM + sh)) * L_DIM + off;
    const _Float16* p2 = E2h + ((size_t)(b * H_DIM + sh)) * L_DIM + off;
    *reinterpret_cast<uint4*>(&e1u[sh][off >> 1]) = *reinterpret_cast<const uint4*>(p1);
    *reinterpret_cast<uint4*>(&e2u[sh][off >> 1]) = *reinterpret_cast<const uint4*>(p2);
  }
  PACK_CHUNK(0, 0);
  LOAD_CHUNK(1);

  const float* RrB = Rr + ((size_t)(b * H_DIM + h)) * L_DIM + i0 + rh * 32 + ln15;
  f16x2 R2g[2];
#pragma unroll
  for (int g = 0; g < 2; ++g) {
    const _Float16 rv = (_Float16)RrB[g * 16];
    R2g[g][0] = rv; R2g[g][1] = rv;
  }
  const _Float16* xb0 = xpT + ((size_t)(b * 128 + h * 32 + ln15)) * 1024;
  const _Float16* xb1 = xb0 + 16 * 1024;

  // 4-deep xpT ring + 2-deep e ring (issue before barrier: hides under it)
  uint4 pf0[4], pf1[4];
#pragma unroll
  for (int s = 0; s < 4; ++s) {
    pf0[s] = *reinterpret_cast<const uint4*>(xb0 + s * 32 + jb);
    pf1[s] = *reinterpret_cast<const uint4*>(xb1 + s * 32 + jb);
  }
  __syncthreads();   // e1/e2 + msk chunk0 visible

  uint4 u1r[2], u2r[2];
#pragma unroll
  for (int s = 0; s < 2; ++s) {
    const int ke = (s * 32 + jb) >> 1;
    u1r[s] = *reinterpret_cast<const uint4*>(&e1u[h][ke]);
    u2r[s] = *reinterpret_cast<const uint4*>(&e2u[h][ke]);
  }

  f32x4 acc0[2] = {}, acc1[2] = {}, accS[2] = {};
  f16x8 ones16;
#pragma unroll
  for (int e = 0; e < 8; ++e) ones16[e] = (_Float16)1.0f;

  int cbuf = 0;
  for (int c = 0; c < 8; ++c) {
    // step 1: this chunk's mask words (1 uint4 per owned row)
    uint4 mwcA = *reinterpret_cast<const uint4*>(&msk[cbuf][rh * 32 + ln15][0]);
    uint4 mwcB = *reinterpret_cast<const uint4*>(&msk[cbuf][rh * 32 + 16 + ln15][0]);
    // step 2: pack next chunk into the other buffer (av holds chunk c+1)
    if (c < 7) PACK_CHUNK(c + 1, cbuf ^ 1);
    // step 3: issue adj loads for chunk c+2
    if (c < 6) LOAD_CHUNK(c + 2);

    // step 4: 4 compute iters (static ring slots: it, it&1)
#pragma unroll
    for (int it = 0; it < 4; ++it) {
      const int kr = c * 128 + it * 32;
      const unsigned wA = (it == 0) ? mwcA.x : (it == 1) ? mwcA.y
                        : (it == 2) ? mwcA.z : mwcA.w;
      const unsigned wB = (it == 0) ? mwcB.x : (it == 1) ? mwcB.y
                        : (it == 2) ? mwcB.z : mwcB.w;
      unsigned mb[2];
      mb[0] = (wA >> (kh * 8)) & 0xffu;
      mb[1] = (wB >> (kh * 8)) & 0xffu;

      // e-ring: consume slot it&1, refill +64 (wrap keeps addr in-bounds)
      const uint4 u1c = u1r[it & 1];
      const uint4 u2c = u2r[it & 1];
      const int kn = (((kr + 64) & 1023) + jb) >> 1;
      u1r[it & 1] = *reinterpret_cast<const uint4*>(&e1u[h][kn]);
      u2r[it & 1] = *reinterpret_cast<const uint4*>(&e2u[h][kn]);

      // xpT ring: consume slot it, refill +128 (over-read lands in ws)
      const uint4 bb0 = pf0[it];
      const uint4 bb1 = pf1[it];
      pf0[it] = *reinterpret_cast<const uint4*>(xb0 + kr + 128 + jb);
      pf1[it] = *reinterpret_cast<const uint4*>(xb1 + kr + 128 + jb);

      const unsigned uu1[4] = {u1c.x, u1c.y, u1c.z, u1c.w};
      const unsigned uu2[4] = {u2c.x, u2c.y, u2c.z, u2c.w};
      unsigned rg[2][4];
#pragma unroll
      for (int q = 0; q < 4; ++q) {
        f16x2 a, ee;
        __builtin_memcpy(&a,  &uu1[q], 4);
        __builtin_memcpy(&ee, &uu2[q], 4);
#pragma unroll
        for (int g = 0; g < 2; ++g) {
          const f16x2 pr2 = ee * R2g[g];                        // v_pk_mul_f16
          const f16x2 mx = __builtin_elementwise_max(a, pr2);   // v_pk_max_f16
          unsigned mu;
          __builtin_memcpy(&mu, &mx, 4);
          const unsigned mlo = (mb[g] & (1u << (2 * q)))     ? 0xFFFFu : 0u;
          const unsigned mhi = (mb[g] & (1u << (2 * q + 1))) ? 0xFFFF0000u : 0u;
          rg[g][q] = mu & (mlo | mhi);
        }
      }
      f16x8 b0h, b1h;
      __builtin_memcpy(&b0h, &bb0, 16);
      __builtin_memcpy(&b1h, &bb1, 16);
      __builtin_amdgcn_s_setprio(1);
#pragma unroll
      for (int g = 0; g < 2; ++g) {
        const uint4 afu = {rg[g][0], rg[g][1], rg[g][2], rg[g][3]};
        f16x8 af;
        __builtin_memcpy(&af, &afu, 16);
        acc0[g] = __builtin_amdgcn_mfma_f32_16x16x32_f16(af, b0h, acc0[g], 0, 0, 0);
        acc1[g] = __builtin_amdgcn_mfma_f32_16x16x32_f16(af, b1h, acc1[g], 0, 0, 0);
        accS[g] = __builtin_amdgcn_mfma_f32_16x16x32_f16(af, ones16, accS[g], 0, 0, 0);
      }
      __builtin_amdgcn_s_setprio(0);
    }
    __syncthreads();   // pack complete + mask reads done before buffer reuse
    cbuf ^= 1;
  }

  // ---- epilogue: waves own complete rows -> direct normalize + store ----
#pragma unroll
  for (int g = 0; g < 2; ++g) {
#pragma unroll
    for (int reg = 0; reg < 4; ++reg) {
      const float rs = 1.0f / accS[g][reg];
      const int row = i0 + rh * 32 + g * 16 + kh * 4 + reg;
      float* op = out + ((size_t)(b * L_DIM + row)) * HC + h * 32;
      op[ln15]      = acc0[g][reg] * rs;
      op[16 + ln15] = acc1[g][reg] * rs;
    }
  }
#undef LOAD_CHUNK
#undef PACK_CHUNK
}

extern "C" void kernel_launch(void* const* d_in, const int* in_sizes, int n_in,
                              void* d_out, int out_size, void* d_ws, size_t ws_size,
                              hipStream_t stream) {
  (void)in_sizes; (void)n_in; (void)out_size; (void)ws_size;
  const float* x        = (const float*)d_in[0];
  const int*   adj      = (const int*)d_in[1];
  const float* W        = (const float*)d_in[2];
  const float* bias     = (const float*)d_in[3];
  const float* att_src  = (const float*)d_in[4];
  const float* att_dst  = (const float*)d_in[5];
  float* out = (float*)d_out;

  char* ws = (char*)d_ws;
  _Float16* xpT = (_Float16*)ws;                                    // 4 MiB
  _Float16* E1h = (_Float16*)(ws + (size_t)4 * 1024 * 1024);        // 128 KiB
  _Float16* E2h = (_Float16*)(ws + (size_t)4 * 1024 * 1024 + 131072);
  float*    Rr  = (float*)(ws + (size_t)4 * 1024 * 1024 + 262144);  // 256 KiB

  hipLaunchKernelGGL(proj_kernel, dim3(B_DIM * L_DIM / 32), dim3(128), 0, stream,
                     x, W, bias, att_src, att_dst, xpT, E1h, E2h, Rr);
  hipLaunchKernelGGL(gat_attn_kernel, dim3(B_DIM * L_DIM / TI), dim3(512), 0, stream,
                     adj, xpT, E1h, E2h, Rr, out);
}